// Round 13
// baseline (94330.743 us; speedup 1.0000x reference)
//
#include <hip/hip_runtime.h>
#include <stdint.h>
#include <math.h>

typedef unsigned int u32;

constexpr int kB = 512, kS = 128, kH = 512, kE = 256, kT = 100;
constexpr int kNG = 4 * kH; // 2048

// ---- ws layout (f32 elements) ----
constexpr size_t SZ_E = (size_t)kS * kB * kH; // 33,554,432
constexpr size_t OFF_EG = 0;
constexpr size_t OFF_EP = OFF_EG + SZ_E;
constexpr size_t OFF_U  = OFF_EP + SZ_E;                 // kB*kS
constexpr size_t OFF_P  = OFF_U + (size_t)kB * kS;       // kB*kS
constexpr size_t OFF_QP = OFF_P + (size_t)kB * kS;       // kB*kH
constexpr size_t OFF_GL = OFF_QP + (size_t)kB * kH;      // kB*kH
constexpr size_t OFF_G  = OFF_GL + (size_t)kB * kH;      // kB*kNG
constexpr size_t OFF_HX = OFF_G + (size_t)kB * kNG;      // kB*kH
constexpr size_t OFF_CX = OFF_HX + (size_t)kB * kH;      // kB*kH
constexpr size_t OFF_DC = OFF_CX + (size_t)kB * kH;      // kB*kE
constexpr size_t OFF_FM = OFF_DC + (size_t)kB * kE;      // kB ints
constexpr size_t OFF_FMM= OFF_FM + kB;
constexpr size_t WS_FLOATS = OFF_FMM + kB;               // ~69.47M f32 = 265 MiB

// ---------------- sentinel (bail only) ----------------
__global__ __launch_bounds__(256) void sentinel_k(float* __restrict__ outSel, float val) {
  int i = blockIdx.x * blockDim.x + threadIdx.x;
  if (i < kT * kB) outSel[i] = val;
}

// ---------------- threefry2x32 (exact JAX) ----------------
__device__ __forceinline__ u32 rotl32(u32 v, int d) { return (v << d) | (v >> (32 - d)); }

__device__ __forceinline__ void tf2x32(u32 k0, u32 k1, u32 x0, u32 x1, u32& o0, u32& o1) {
  u32 ks2 = k0 ^ k1 ^ 0x1BD11BDAu;
  x0 += k0; x1 += k1;
#define RND_(r) { x0 += x1; x1 = rotl32(x1, r); x1 ^= x0; }
  RND_(13) RND_(15) RND_(26) RND_(6)   x0 += k1;  x1 += ks2 + 1u;
  RND_(17) RND_(29) RND_(16) RND_(24)  x0 += ks2; x1 += k0 + 2u;
  RND_(13) RND_(15) RND_(26) RND_(6)   x0 += k0;  x1 += k1 + 3u;
  RND_(17) RND_(29) RND_(16) RND_(24)  x0 += k1;  x1 += ks2 + 4u;
  RND_(13) RND_(15) RND_(26) RND_(6)   x0 += ks2; x1 += k0 + 5u;
#undef RND_
  o0 = x0; o1 = x1;
}

__device__ __forceinline__ float sigf(float x) { return 1.0f / (1.0f + expf(-x)); }

// ------- E precompute: EG/EP[(s*B+b)][o] = serial_h fmaf(ctx, W) + bias; m-tile=8 -------
__global__ __launch_bounds__(512) void precompute_e(const float* __restrict__ ctx,
                                                    const float* __restrict__ Wg,
                                                    const float* __restrict__ bg,
                                                    const float* __restrict__ Wp,
                                                    const float* __restrict__ bp,
                                                    float* __restrict__ EG,
                                                    float* __restrict__ EP) {
  __shared__ float ctxs[8][512];
  __shared__ float Wgs[512][33];
  __shared__ float Wps[512][33];
  const int tid = threadIdx.x;
  const size_t m0 = (size_t)blockIdx.x * 8;
  for (int idx = tid; idx < 8 * 512; idx += 512) {
    int mi = idx >> 9, k = idx & 511;
    ctxs[mi][k] = ctx[(m0 + mi) * 512 + k];
  }
  float accg[8] = {}, accp[8] = {};
  for (int k0 = 0; k0 < 512; k0 += 32) {
    __syncthreads();
    const float4* sg = (const float4*)&Wg[(size_t)tid * 512 + k0];
    const float4* sp = (const float4*)&Wp[(size_t)tid * 512 + k0];
#pragma unroll
    for (int q = 0; q < 8; ++q) {
      float4 v = sg[q];
      Wgs[tid][q * 4 + 0] = v.x; Wgs[tid][q * 4 + 1] = v.y;
      Wgs[tid][q * 4 + 2] = v.z; Wgs[tid][q * 4 + 3] = v.w;
      float4 w = sp[q];
      Wps[tid][q * 4 + 0] = w.x; Wps[tid][q * 4 + 1] = w.y;
      Wps[tid][q * 4 + 2] = w.z; Wps[tid][q * 4 + 3] = w.w;
    }
    __syncthreads();
#pragma unroll 4
    for (int kk = 0; kk < 32; ++kk) {
      float wg = Wgs[tid][kk], wp = Wps[tid][kk];
#pragma unroll
      for (int mi = 0; mi < 8; ++mi) {
        float a = ctxs[mi][k0 + kk];
        accg[mi] = fmaf(a, wg, accg[mi]);
        accp[mi] = fmaf(a, wp, accp[mi]);
      }
    }
  }
  float bgv = bg[tid], bpv = bp[tid];
#pragma unroll
  for (int mi = 0; mi < 8; ++mi) {
    EG[(m0 + mi) * 512 + tid] = accg[mi] + bgv;
    EP[(m0 + mi) * 512 + tid] = accp[mi] + bpv;
  }
}

// ------- serial-k NT GEMM: C[b][o] = ((Cin) + sum_k A[b,k]*W[o,k]) + bias[o] -------
template <int K, bool FIRST>
__global__ __launch_bounds__(512) void gemm_serial(const float* __restrict__ A,
                                                   const float* __restrict__ W,
                                                   const float* __restrict__ bias,
                                                   const float* __restrict__ Cin,
                                                   float* __restrict__ C, int N) {
  __shared__ float As[K];
  __shared__ float Ws[512][33];
  const int b = blockIdx.y;
  const int o0 = blockIdx.x * 512;
  const int tid = threadIdx.x;
  for (int i = tid; i < K; i += 512) As[i] = A[(size_t)b * K + i];
  float acc = 0.f;
  for (int k0 = 0; k0 < K; k0 += 32) {
    __syncthreads();
    const float4* src = (const float4*)&W[(size_t)(o0 + tid) * K + k0];
#pragma unroll
    for (int q = 0; q < 8; ++q) {
      float4 v = src[q];
      Ws[tid][q * 4 + 0] = v.x; Ws[tid][q * 4 + 1] = v.y;
      Ws[tid][q * 4 + 2] = v.z; Ws[tid][q * 4 + 3] = v.w;
    }
    __syncthreads();
#pragma unroll 8
    for (int kk = 0; kk < 32; ++kk) acc = fmaf(As[k0 + kk], Ws[tid][kk], acc);
  }
  size_t off = (size_t)b * N + o0 + tid;
  if (FIRST) C[off] = acc + bias[o0 + tid];
  else       C[off] = (Cin[off] + acc) + bias[o0 + tid];
}

// ---------------- init state (f32) ----------------
__global__ __launch_bounds__(256) void init_k(const float* __restrict__ dec_in,
                                              const float* __restrict__ hx0,
                                              const float* __restrict__ cx0,
                                              float* __restrict__ dec, float* __restrict__ hx,
                                              float* __restrict__ cx, int* __restrict__ fm,
                                              int* __restrict__ fmm) {
  int i = blockIdx.x * blockDim.x + threadIdx.x;
  if (i < kB * kH) { hx[i] = hx0[i]; cx[i] = cx0[i]; }
  if (i < kB * kE) dec[i] = dec_in[i];
  if (i < kB) { fm[i] = 1; fmm[i] = 1; }
}

// ---------------- LSTM elementwise (f32) ----------------
__global__ __launch_bounds__(256) void lstm_act(const float* __restrict__ gates,
                                                float* __restrict__ hx, float* __restrict__ cx) {
  int i = blockIdx.x * blockDim.x + threadIdx.x;
  int b = i >> 9, h = i & (kH - 1);
  const float* g = gates + (size_t)b * kNG;
  float ig = g[h], fg = g[h + kH], cg = g[h + 2 * kH], og = g[h + 3 * kH];
  float cyv = sigf(fg) * cx[i] + sigf(ig) * tanhf(cg);
  float hyv = sigf(og) * tanhf(cyv);
  cx[i] = cyv;
  hx[i] = hyv;
}

// ------- u[b][s] = serial_h fmaf(v[h], tanhf(qp[b][h] + e[s][b][h])) -------
__global__ __launch_bounds__(128) void att_u(const float* __restrict__ e,
                                             const float* __restrict__ qp,
                                             const float* __restrict__ v,
                                             float* __restrict__ U) {
  __shared__ float qs[512], vs[512];
  const int b = blockIdx.x;
  const int s = threadIdx.x;
  for (int i = s; i < 512; i += 128) {
    qs[i] = qp[(size_t)b * 512 + i];
    vs[i] = v[i];
  }
  __syncthreads();
  const float* row = e + ((size_t)s * kB + b) * kH;
  float acc = 0.f;
  for (int h = 0; h < 512; ++h) acc = fmaf(vs[h], tanhf(qs[h] + row[h]), acc);
  U[(size_t)b * kS + s] = acc;
}

// ------- softmax over s, serial max & serial sum -------
__global__ __launch_bounds__(128) void softmax_k(const float* __restrict__ U,
                                                 float* __restrict__ P) {
  __shared__ float us[128], ex[128];
  __shared__ float mred, sred;
  int b = blockIdx.x, s = threadIdx.x;
  us[s] = U[(size_t)b * kS + s];
  __syncthreads();
  if (s == 0) { float m = us[0]; for (int i = 1; i < 128; ++i) m = fmaxf(m, us[i]); mred = m; }
  __syncthreads();
  ex[s] = expf(us[s] - mred);
  __syncthreads();
  if (s == 0) { float t = 0.f; for (int i = 0; i < 128; ++i) t += ex[i]; sred = t; }
  __syncthreads();
  P[(size_t)b * kS + s] = ex[s] / sred;
}

// ------- GL[b][h] = serial_s fmaf(EG[s][b][h], P[b][s]) -------
__global__ __launch_bounds__(512) void gl_k(const float* __restrict__ eg,
                                            const float* __restrict__ P,
                                            float* __restrict__ GL) {
  __shared__ float ps[128];
  int b = blockIdx.x, h = threadIdx.x;
  if (h < 128) ps[h] = P[(size_t)b * kS + h];
  __syncthreads();
  float acc = 0.f;
  for (int s = 0; s < 128; ++s) acc = fmaf(eg[((size_t)s * kB + b) * kH + h], ps[s], acc);
  GL[(size_t)b * kH + h] = acc;
}

// ------- logits + softmax + gumbel(partitionable XOR) + argmax + masks + gather -------
__global__ __launch_bounds__(256) void sample_k(const float* __restrict__ U2,
                                                const float* __restrict__ emb,
                                                const int* __restrict__ counts,
                                                float* __restrict__ dec, int* __restrict__ fmask,
                                                int* __restrict__ fmmask,
                                                float* __restrict__ outP,
                                                float* __restrict__ outSel, int t) {
  __shared__ float sL[128], ex[128], kv[128];
  __shared__ float mred, sred, sMult;
  __shared__ int sIdx;
  int b = blockIdx.x, tid = threadIdx.x;
  if (tid < 128) sL[tid] = 10.0f * tanhf(U2[(size_t)b * kS + tid]);
  __syncthreads();
  if (tid == 0) { float m = sL[0]; for (int i = 1; i < 128; ++i) m = fmaxf(m, sL[i]); mred = m; }
  __syncthreads();
  if (tid < 128) ex[tid] = expf(sL[tid] - mred);
  __syncthreads();
  if (tid == 0) { float s = 0.f; for (int i = 0; i < 128; ++i) s += ex[i]; sred = s; }
  __syncthreads();
  if (tid < 128) {
    // folded key for step t: threefry((0,42),(0,t))  [fold_in is mode-independent]
    u32 fk0, fk1;
    tf2x32(0u, 42u, 0u, (u32)t, fk0, fk1);
    // PARTITIONABLE 32-bit path (modern JAX default): element j -> counter (0, j);
    // u32 bits = out0 XOR out1   (prng.py: `bits1 ^ bits2`, NOT 64-bit pack truncation)
    u32 j = (u32)(b * kS + tid);
    u32 y0, y1;
    tf2x32(fk0, fk1, 0u, j, y0, y1);
    u32 bits = y0 ^ y1;
    float f = __uint_as_float(0x3f800000u | (bits >> 9)) - 1.0f;
    float uu = (f > 0.0f) ? f : 1.17549435082228751e-38f;
    float z = -logf(-logf(uu));
    kv[tid] = sL[tid] + z;
  }
  __syncthreads();
  if (tid == 0) {
    float best = kv[0];
    int ia = 0;
    for (int i = 1; i < 128; ++i)
      if (kv[i] > best) { best = kv[i]; ia = i; } // first-index tie-break
    int fm = fmask[b], fmm = fmmask[b];
    int idx = ia * fm;
    outSel[(size_t)t * kB + b] = (float)idx; // honest
    fmask[b] = (idx != 0) ? fm : 0;
    fmmask[b] = (t == counts[b]) ? 0 : fmm;
    sIdx = idx;
    sMult = (float)(fm * fmm);
  }
  __syncthreads();
  if (tid < 128) outP[((size_t)b * kT + t) * kS + tid] = (ex[tid] / sred) * sMult;
  if (tid < 256) dec[(size_t)b * kE + tid] = emb[((size_t)sIdx * kB + b) * kE + tid];
}

// ---------------- final hx/cx copy ----------------
__global__ __launch_bounds__(256) void final_copy(const float* __restrict__ hx,
                                                  const float* __restrict__ cx,
                                                  float* __restrict__ o2, float* __restrict__ o3) {
  int i = blockIdx.x * blockDim.x + threadIdx.x;
  if (i < kB * kH) { o2[i] = hx[i]; o3[i] = cx[i]; }
}

extern "C" void kernel_launch(void* const* d_in, const int* in_sizes, int n_in, void* d_out,
                              int out_size, void* d_ws, size_t ws_size, hipStream_t stream) {
  const float* dec_in = (const float*)d_in[0];
  const float* emb = (const float*)d_in[1];
  const float* hx0 = (const float*)d_in[2];
  const float* cx0 = (const float*)d_in[3];
  const float* ctx = (const float*)d_in[4];
  const int* counts = (const int*)d_in[5];
  const float* Wi = (const float*)d_in[7];
  const float* bi = (const float*)d_in[8];
  const float* Wh = (const float*)d_in[9];
  const float* bh = (const float*)d_in[10];
  const float* gWq = (const float*)d_in[11];
  const float* gbq = (const float*)d_in[12];
  const float* gWr = (const float*)d_in[13];
  const float* gbr = (const float*)d_in[14];
  const float* gv = (const float*)d_in[15];
  const float* pWq = (const float*)d_in[16];
  const float* pbq = (const float*)d_in[17];
  const float* pWr = (const float*)d_in[18];
  const float* pbr = (const float*)d_in[19];
  const float* pv = (const float*)d_in[20];

  float* out = (float*)d_out;
  float* outP = out;                          // (B*T, S)
  float* outSel = out + (size_t)kB * kT * kS; // (T, B)
  float* outHx = outSel + (size_t)kT * kB;    // (B, H)
  float* outCx = outHx + (size_t)kB * kH;     // (B, H)

  if (ws_size < WS_FLOATS * sizeof(float)) {
    double wsMB = (double)ws_size / (1024.0 * 1024.0);
    if (wsMB > 80000.0) wsMB = 80000.0;
    hipLaunchKernelGGL(sentinel_k, dim3((kT * kB + 255) / 256), dim3(256), 0, stream, outSel,
                       (float)(1000.0 + wsMB));
    return;
  }

  float* base = (float*)d_ws;
  float* EG = base + OFF_EG;
  float* EP = base + OFF_EP;
  float* U  = base + OFF_U;
  float* P  = base + OFF_P;
  float* QP = base + OFF_QP;
  float* GL = base + OFF_GL;
  float* G  = base + OFF_G;
  float* HX = base + OFF_HX;
  float* CX = base + OFF_CX;
  float* DC = base + OFF_DC;
  int* FM = (int*)(base + OFF_FM);
  int* FMM = (int*)(base + OFF_FMM);

  hipLaunchKernelGGL(precompute_e, dim3(kS * kB / 8), dim3(512), 0, stream, ctx, gWr, gbr, pWr,
                     pbr, EG, EP);
  hipLaunchKernelGGL(init_k, dim3(kB * kH / 256), dim3(256), 0, stream, dec_in, hx0, cx0, DC, HX,
                     CX, FM, FMM);

  for (int t = 0; t < kT; ++t) {
    hipLaunchKernelGGL((gemm_serial<256, true>), dim3(4, kB), dim3(512), 0, stream, DC, Wi, bi,
                       (const float*)nullptr, G, kNG);
    hipLaunchKernelGGL((gemm_serial<512, false>), dim3(4, kB), dim3(512), 0, stream, HX, Wh, bh, G,
                       G, kNG);
    hipLaunchKernelGGL(lstm_act, dim3(kB * kH / 256), dim3(256), 0, stream, G, HX, CX);
    hipLaunchKernelGGL((gemm_serial<512, true>), dim3(1, kB), dim3(512), 0, stream, HX, gWq, gbq,
                       (const float*)nullptr, QP, kH);
    hipLaunchKernelGGL(att_u, dim3(kB), dim3(128), 0, stream, EG, QP, gv, U);
    hipLaunchKernelGGL(softmax_k, dim3(kB), dim3(128), 0, stream, U, P);
    hipLaunchKernelGGL(gl_k, dim3(kB), dim3(512), 0, stream, EG, P, GL);
    hipLaunchKernelGGL((gemm_serial<512, true>), dim3(1, kB), dim3(512), 0, stream, GL, pWq, pbq,
                       (const float*)nullptr, QP, kH);
    hipLaunchKernelGGL(att_u, dim3(kB), dim3(128), 0, stream, EP, QP, pv, U);
    hipLaunchKernelGGL(sample_k, dim3(kB), dim3(256), 0, stream, U, emb, counts, DC, FM, FMM, outP,
                       outSel, t);
  }
  hipLaunchKernelGGL(final_copy, dim3(kB * kH / 256), dim3(256), 0, stream, HX, CX, outHx, outCx);
}

// Round 14
// 83635.852 us; speedup vs baseline: 1.1279x; 1.1279x over previous
//
#include <hip/hip_runtime.h>
#include <stdint.h>
#include <math.h>

typedef unsigned int u32;

constexpr int kB = 512, kS = 128, kH = 512, kE = 256, kT = 100;
constexpr int kNG = 4 * kH; // 2048

// ---- ws layout (f32 elements) ----
constexpr size_t SZ_E = (size_t)kS * kB * kH; // 33,554,432
constexpr size_t OFF_EG  = 0;                              // EG original [s][b][h] (gl_k, tier2 att1)
constexpr size_t OFF_EPT = OFF_EG + SZ_E;                  // EP transposed [b][h][s] (att2)
constexpr size_t OFF_U   = OFF_EPT + SZ_E;                 // kB*kS
constexpr size_t OFF_P   = OFF_U + (size_t)kB * kS;        // kB*kS
constexpr size_t OFF_QP  = OFF_P + (size_t)kB * kS;        // kB*kH
constexpr size_t OFF_GL  = OFF_QP + (size_t)kB * kH;       // kB*kH
constexpr size_t OFF_G   = OFF_GL + (size_t)kB * kH;       // kB*kNG
constexpr size_t OFF_HX  = OFF_G + (size_t)kB * kNG;       // kB*kH
constexpr size_t OFF_CX  = OFF_HX + (size_t)kB * kH;       // kB*kH
constexpr size_t OFF_DC  = OFF_CX + (size_t)kB * kH;       // kB*kE
constexpr size_t OFF_FM  = OFF_DC + (size_t)kB * kE;       // kB ints
constexpr size_t OFF_FMM = OFF_FM + kB;
constexpr size_t OFF_EGT = OFF_FMM + kB;                   // EG transposed (tier1 only)
constexpr size_t WS_T2 = OFF_EGT;                          // ≈69.47M f32 = 265 MiB (PROVEN: R13 ran)
constexpr size_t WS_T1 = OFF_EGT + SZ_E;                   // ≈412 MiB (tier1 if available)

// ---------------- sentinel (bail only) ----------------
__global__ __launch_bounds__(256) void sentinel_k(float* __restrict__ outSel, float val) {
  int i = blockIdx.x * blockDim.x + threadIdx.x;
  if (i < kT * kB) outSel[i] = val;
}

// ---------------- threefry2x32 (exact JAX) ----------------
__device__ __forceinline__ u32 rotl32(u32 v, int d) { return (v << d) | (v >> (32 - d)); }

__device__ __forceinline__ void tf2x32(u32 k0, u32 k1, u32 x0, u32 x1, u32& o0, u32& o1) {
  u32 ks2 = k0 ^ k1 ^ 0x1BD11BDAu;
  x0 += k0; x1 += k1;
#define RND_(r) { x0 += x1; x1 = rotl32(x1, r); x1 ^= x0; }
  RND_(13) RND_(15) RND_(26) RND_(6)   x0 += k1;  x1 += ks2 + 1u;
  RND_(17) RND_(29) RND_(16) RND_(24)  x0 += ks2; x1 += k0 + 2u;
  RND_(13) RND_(15) RND_(26) RND_(6)   x0 += k0;  x1 += k1 + 3u;
  RND_(17) RND_(29) RND_(16) RND_(24)  x0 += k1;  x1 += ks2 + 4u;
  RND_(13) RND_(15) RND_(26) RND_(6)   x0 += ks2; x1 += k0 + 5u;
#undef RND_
  o0 = x0; o1 = x1;
}

__device__ __forceinline__ float sigf(float x) { return 1.0f / (1.0f + expf(-x)); }

// ------- E precompute: coalesced W staging; writes EG orig + EPt (+ EGt tier1) -------
// identical per-output serial-k fmaf accumulation as R13 (bit-exact)
template <bool EGT>
__global__ __launch_bounds__(512) void precompute_e(const float* __restrict__ ctx,
                                                    const float* __restrict__ Wg,
                                                    const float* __restrict__ bg,
                                                    const float* __restrict__ Wp,
                                                    const float* __restrict__ bp,
                                                    float* __restrict__ EG,
                                                    float* __restrict__ EPt,
                                                    float* __restrict__ EGt) {
  __shared__ float ctxs[8][512];
  __shared__ float Wgs[512][33];
  __shared__ float Wps[512][33];
  const int tid = threadIdx.x;
  const size_t m0 = (size_t)blockIdx.x * 8;
  for (int idx = tid; idx < 8 * 512; idx += 512) {
    ctxs[idx >> 9][idx & 511] = ctx[(m0 + (idx >> 9)) * 512 + (idx & 511)];
  }
  float accg[8] = {}, accp[8] = {};
  for (int k0 = 0; k0 < 512; k0 += 32) {
    __syncthreads();
    // cooperative coalesced staging: consecutive lanes -> consecutive kk within a row
    for (int idx = tid; idx < 512 * 32; idx += 512) {
      int row = idx >> 5, kk = idx & 31;
      Wgs[row][kk] = Wg[(size_t)row * 512 + k0 + kk];
      Wps[row][kk] = Wp[(size_t)row * 512 + k0 + kk];
    }
    __syncthreads();
#pragma unroll 4
    for (int kk = 0; kk < 32; ++kk) {
      float wg = Wgs[tid][kk], wp = Wps[tid][kk];
#pragma unroll
      for (int mi = 0; mi < 8; ++mi) {
        float a = ctxs[mi][k0 + kk];
        accg[mi] = fmaf(a, wg, accg[mi]);
        accp[mi] = fmaf(a, wp, accp[mi]);
      }
    }
  }
  float bgv = bg[tid], bpv = bp[tid];
#pragma unroll
  for (int mi = 0; mi < 8; ++mi) {
    size_t m = m0 + mi;
    int b = (int)(m & 511), s = (int)(m >> 9);
    float eg = accg[mi] + bgv;
    float ep = accp[mi] + bpv;
    EG[m * 512 + tid] = eg;
    EPt[((size_t)b * 512 + tid) * 128 + s] = ep;
    if (EGT) EGt[((size_t)b * 512 + tid) * 128 + s] = eg;
  }
}

// ------- b-tiled serial-k NT GEMM: per-output exact ascending-k fmaf (bit-exact) -------
// grid (N/512, B/NB), block 512; coalesced cooperative W staging
template <int K, int NB, bool FIRST>
__global__ __launch_bounds__(512) void gemm_v2(const float* __restrict__ A,
                                               const float* __restrict__ W,
                                               const float* __restrict__ bias,
                                               const float* __restrict__ Cin,
                                               float* __restrict__ C, int N) {
  __shared__ float As[NB][K];
  __shared__ float Ws[512][33];
  const int b0 = blockIdx.y * NB;
  const int o0 = blockIdx.x * 512;
  const int tid = threadIdx.x;
  for (int idx = tid; idx < NB * K; idx += 512) {
    int bb = idx / K, k = idx % K;
    As[bb][k] = A[(size_t)(b0 + bb) * K + k];
  }
  float acc[NB] = {};
  for (int k0 = 0; k0 < K; k0 += 32) {
    __syncthreads();
    for (int idx = tid; idx < 512 * 32; idx += 512) {
      int row = idx >> 5, kk = idx & 31;
      Ws[row][kk] = W[(size_t)(o0 + row) * K + k0 + kk];
    }
    __syncthreads();
#pragma unroll 4
    for (int kk = 0; kk < 32; ++kk) {
      float w = Ws[tid][kk];
#pragma unroll
      for (int bb = 0; bb < NB; ++bb) acc[bb] = fmaf(As[bb][k0 + kk], w, acc[bb]);
    }
  }
  float bv = bias[o0 + tid];
#pragma unroll
  for (int bb = 0; bb < NB; ++bb) {
    size_t off = (size_t)(b0 + bb) * N + o0 + tid;
    C[off] = FIRST ? (acc[bb] + bv) : ((Cin[off] + acc[bb]) + bv);
  }
}

// ---------------- init state (f32) ----------------
__global__ __launch_bounds__(256) void init_k(const float* __restrict__ dec_in,
                                              const float* __restrict__ hx0,
                                              const float* __restrict__ cx0,
                                              float* __restrict__ dec, float* __restrict__ hx,
                                              float* __restrict__ cx, int* __restrict__ fm,
                                              int* __restrict__ fmm) {
  int i = blockIdx.x * blockDim.x + threadIdx.x;
  if (i < kB * kH) { hx[i] = hx0[i]; cx[i] = cx0[i]; }
  if (i < kB * kE) dec[i] = dec_in[i];
  if (i < kB) { fm[i] = 1; fmm[i] = 1; }
}

// ---------------- LSTM elementwise (f32) ----------------
__global__ __launch_bounds__(256) void lstm_act(const float* __restrict__ gates,
                                                float* __restrict__ hx, float* __restrict__ cx) {
  int i = blockIdx.x * blockDim.x + threadIdx.x;
  int b = i >> 9, h = i & (kH - 1);
  const float* g = gates + (size_t)b * kNG;
  float ig = g[h], fg = g[h + kH], cg = g[h + 2 * kH], og = g[h + 3 * kH];
  float cyv = sigf(fg) * cx[i] + sigf(ig) * tanhf(cg);
  float hyv = sigf(og) * tanhf(cyv);
  cx[i] = cyv;
  hx[i] = hyv;
}

// ------- att on TRANSPOSED E [b][h][s]: coalesced; exact ascending-h fmaf chain -------
__global__ __launch_bounds__(128) void att_t(const float* __restrict__ Et,
                                             const float* __restrict__ qp,
                                             const float* __restrict__ v,
                                             float* __restrict__ U) {
  __shared__ float qs[512], vs[512];
  const int b = blockIdx.x;
  const int s = threadIdx.x;
  for (int i = s; i < 512; i += 128) {
    qs[i] = qp[(size_t)b * 512 + i];
    vs[i] = v[i];
  }
  __syncthreads();
  const float* base = Et + (size_t)b * 512 * 128 + s;
  float acc = 0.f;
  for (int h = 0; h < 512; ++h) acc = fmaf(vs[h], tanhf(qs[h] + base[(size_t)h * 128]), acc);
  U[(size_t)b * kS + s] = acc;
}

// ------- att on ORIGINAL E [s][b][h] (tier2 att1 fallback; exact, gather-bound) -------
__global__ __launch_bounds__(128) void att_u(const float* __restrict__ e,
                                             const float* __restrict__ qp,
                                             const float* __restrict__ v,
                                             float* __restrict__ U) {
  __shared__ float qs[512], vs[512];
  const int b = blockIdx.x;
  const int s = threadIdx.x;
  for (int i = s; i < 512; i += 128) {
    qs[i] = qp[(size_t)b * 512 + i];
    vs[i] = v[i];
  }
  __syncthreads();
  const float* row = e + ((size_t)s * kB + b) * kH;
  float acc = 0.f;
  for (int h = 0; h < 512; ++h) acc = fmaf(vs[h], tanhf(qs[h] + row[h]), acc);
  U[(size_t)b * kS + s] = acc;
}

// ------- softmax over s, serial max & serial sum -------
__global__ __launch_bounds__(128) void softmax_k(const float* __restrict__ U,
                                                 float* __restrict__ P) {
  __shared__ float us[128], ex[128];
  __shared__ float mred, sred;
  int b = blockIdx.x, s = threadIdx.x;
  us[s] = U[(size_t)b * kS + s];
  __syncthreads();
  if (s == 0) { float m = us[0]; for (int i = 1; i < 128; ++i) m = fmaxf(m, us[i]); mred = m; }
  __syncthreads();
  ex[s] = expf(us[s] - mred);
  __syncthreads();
  if (s == 0) { float t = 0.f; for (int i = 0; i < 128; ++i) t += ex[i]; sred = t; }
  __syncthreads();
  P[(size_t)b * kS + s] = ex[s] / sred;
}

// ------- GL[b][h] = serial_s fmaf(EG[s][b][h], P[b][s])  (coalesced over h, exact) -------
__global__ __launch_bounds__(512) void gl_k(const float* __restrict__ eg,
                                            const float* __restrict__ P,
                                            float* __restrict__ GL) {
  __shared__ float ps[128];
  int b = blockIdx.x, h = threadIdx.x;
  if (h < 128) ps[h] = P[(size_t)b * kS + h];
  __syncthreads();
  float acc = 0.f;
  for (int s = 0; s < 128; ++s) acc = fmaf(eg[((size_t)s * kB + b) * kH + h], ps[s], acc);
  GL[(size_t)b * kH + h] = acc;
}

// ------- logits + softmax + gumbel(partitionable XOR) + argmax + masks + gather -------
__global__ __launch_bounds__(256) void sample_k(const float* __restrict__ U2,
                                                const float* __restrict__ emb,
                                                const int* __restrict__ counts,
                                                float* __restrict__ dec, int* __restrict__ fmask,
                                                int* __restrict__ fmmask,
                                                float* __restrict__ outP,
                                                float* __restrict__ outSel, int t) {
  __shared__ float sL[128], ex[128], kv[128];
  __shared__ float mred, sred, sMult;
  __shared__ int sIdx;
  int b = blockIdx.x, tid = threadIdx.x;
  if (tid < 128) sL[tid] = 10.0f * tanhf(U2[(size_t)b * kS + tid]);
  __syncthreads();
  if (tid == 0) { float m = sL[0]; for (int i = 1; i < 128; ++i) m = fmaxf(m, sL[i]); mred = m; }
  __syncthreads();
  if (tid < 128) ex[tid] = expf(sL[tid] - mred);
  __syncthreads();
  if (tid == 0) { float s = 0.f; for (int i = 0; i < 128; ++i) s += ex[i]; sred = s; }
  __syncthreads();
  if (tid < 128) {
    u32 fk0, fk1;
    tf2x32(0u, 42u, 0u, (u32)t, fk0, fk1);
    // partitionable 32-bit path: counter (0, j); bits = out0 ^ out1
    u32 j = (u32)(b * kS + tid);
    u32 y0, y1;
    tf2x32(fk0, fk1, 0u, j, y0, y1);
    u32 bits = y0 ^ y1;
    float f = __uint_as_float(0x3f800000u | (bits >> 9)) - 1.0f;
    float uu = (f > 0.0f) ? f : 1.17549435082228751e-38f;
    float z = -logf(-logf(uu));
    kv[tid] = sL[tid] + z;
  }
  __syncthreads();
  if (tid == 0) {
    float best = kv[0];
    int ia = 0;
    for (int i = 1; i < 128; ++i)
      if (kv[i] > best) { best = kv[i]; ia = i; } // first-index tie-break
    int fm = fmask[b], fmm = fmmask[b];
    int idx = ia * fm;
    outSel[(size_t)t * kB + b] = (float)idx;
    fmask[b] = (idx != 0) ? fm : 0;
    fmmask[b] = (t == counts[b]) ? 0 : fmm;
    sIdx = idx;
    sMult = (float)(fm * fmm);
  }
  __syncthreads();
  if (tid < 128) outP[((size_t)b * kT + t) * kS + tid] = (ex[tid] / sred) * sMult;
  if (tid < 256) dec[(size_t)b * kE + tid] = emb[((size_t)sIdx * kB + b) * kE + tid];
}

// ---------------- final hx/cx copy ----------------
__global__ __launch_bounds__(256) void final_copy(const float* __restrict__ hx,
                                                  const float* __restrict__ cx,
                                                  float* __restrict__ o2, float* __restrict__ o3) {
  int i = blockIdx.x * blockDim.x + threadIdx.x;
  if (i < kB * kH) { o2[i] = hx[i]; o3[i] = cx[i]; }
}

extern "C" void kernel_launch(void* const* d_in, const int* in_sizes, int n_in, void* d_out,
                              int out_size, void* d_ws, size_t ws_size, hipStream_t stream) {
  const float* dec_in = (const float*)d_in[0];
  const float* emb = (const float*)d_in[1];
  const float* hx0 = (const float*)d_in[2];
  const float* cx0 = (const float*)d_in[3];
  const float* ctx = (const float*)d_in[4];
  const int* counts = (const int*)d_in[5];
  const float* Wi = (const float*)d_in[7];
  const float* bi = (const float*)d_in[8];
  const float* Wh = (const float*)d_in[9];
  const float* bh = (const float*)d_in[10];
  const float* gWq = (const float*)d_in[11];
  const float* gbq = (const float*)d_in[12];
  const float* gWr = (const float*)d_in[13];
  const float* gbr = (const float*)d_in[14];
  const float* gv = (const float*)d_in[15];
  const float* pWq = (const float*)d_in[16];
  const float* pbq = (const float*)d_in[17];
  const float* pWr = (const float*)d_in[18];
  const float* pbr = (const float*)d_in[19];
  const float* pv = (const float*)d_in[20];

  float* out = (float*)d_out;
  float* outP = out;                          // (B*T, S)
  float* outSel = out + (size_t)kB * kT * kS; // (T, B)
  float* outHx = outSel + (size_t)kT * kB;    // (B, H)
  float* outCx = outHx + (size_t)kB * kH;     // (B, H)

  if (ws_size < WS_T2 * sizeof(float)) {
    double wsMB = (double)ws_size / (1024.0 * 1024.0);
    if (wsMB > 80000.0) wsMB = 80000.0;
    hipLaunchKernelGGL(sentinel_k, dim3((kT * kB + 255) / 256), dim3(256), 0, stream, outSel,
                       (float)(1000.0 + wsMB));
    return;
  }
  const bool tier1 = ws_size >= WS_T1 * sizeof(float);

  float* base = (float*)d_ws;
  float* EG  = base + OFF_EG;
  float* EPt = base + OFF_EPT;
  float* U   = base + OFF_U;
  float* P   = base + OFF_P;
  float* QP  = base + OFF_QP;
  float* GL  = base + OFF_GL;
  float* G   = base + OFF_G;
  float* HX  = base + OFF_HX;
  float* CX  = base + OFF_CX;
  float* DC  = base + OFF_DC;
  int* FM  = (int*)(base + OFF_FM);
  int* FMM = (int*)(base + OFF_FMM);
  float* EGt = base + OFF_EGT; // valid only if tier1

  if (tier1) {
    hipLaunchKernelGGL((precompute_e<true>), dim3(kS * kB / 8), dim3(512), 0, stream, ctx, gWr,
                       gbr, pWr, pbr, EG, EPt, EGt);
  } else {
    hipLaunchKernelGGL((precompute_e<false>), dim3(kS * kB / 8), dim3(512), 0, stream, ctx, gWr,
                       gbr, pWr, pbr, EG, EPt, (float*)nullptr);
  }
  hipLaunchKernelGGL(init_k, dim3(kB * kH / 256), dim3(256), 0, stream, dec_in, hx0, cx0, DC, HX,
                     CX, FM, FMM);

  for (int t = 0; t < kT; ++t) {
    hipLaunchKernelGGL((gemm_v2<256, 8, true>), dim3(4, 64), dim3(512), 0, stream, DC, Wi, bi,
                       (const float*)nullptr, G, kNG);
    hipLaunchKernelGGL((gemm_v2<512, 8, false>), dim3(4, 64), dim3(512), 0, stream, HX, Wh, bh, G,
                       G, kNG);
    hipLaunchKernelGGL(lstm_act, dim3(kB * kH / 256), dim3(256), 0, stream, G, HX, CX);
    hipLaunchKernelGGL((gemm_v2<512, 4, true>), dim3(1, 128), dim3(512), 0, stream, HX, gWq, gbq,
                       (const float*)nullptr, QP, kH);
    if (tier1) {
      hipLaunchKernelGGL(att_t, dim3(kB), dim3(128), 0, stream, EGt, QP, gv, U);
    } else {
      hipLaunchKernelGGL(att_u, dim3(kB), dim3(128), 0, stream, EG, QP, gv, U);
    }
    hipLaunchKernelGGL(softmax_k, dim3(kB), dim3(128), 0, stream, U, P);
    hipLaunchKernelGGL(gl_k, dim3(kB), dim3(512), 0, stream, EG, P, GL);
    hipLaunchKernelGGL((gemm_v2<512, 4, true>), dim3(1, 128), dim3(512), 0, stream, GL, pWq, pbq,
                       (const float*)nullptr, QP, kH);
    hipLaunchKernelGGL(att_t, dim3(kB), dim3(128), 0, stream, EPt, QP, pv, U);
    hipLaunchKernelGGL(sample_k, dim3(kB), dim3(256), 0, stream, U, emb, counts, DC, FM, FMM, outP,
                       outSel, t);
  }
  hipLaunchKernelGGL(final_copy, dim3(kB * kH / 256), dim3(256), 0, stream, HX, CX, outHx, outCx);
}

// Round 15
// 36142.279 us; speedup vs baseline: 2.6100x; 2.3141x over previous
//
#include <hip/hip_runtime.h>
#include <stdint.h>
#include <math.h>

typedef unsigned int u32;

constexpr int kB = 512, kS = 128, kH = 512, kE = 256, kT = 100;
constexpr int kNG = 4 * kH; // 2048

// ---- ws layout (f32 elements) ----
constexpr size_t SZ_E = (size_t)kS * kB * kH; // 33,554,432
constexpr size_t OFF_EG  = 0;                              // EG [s][b][h]
constexpr size_t OFF_EP  = OFF_EG + SZ_E;                  // EP [s][b][h]
constexpr size_t OFF_U   = OFF_EP + SZ_E;                  // (unused, kept for layout stability)
constexpr size_t OFF_P   = OFF_U + (size_t)kB * kS;
constexpr size_t OFF_QP  = OFF_P + (size_t)kB * kS;
constexpr size_t OFF_GL  = OFF_QP + (size_t)kB * kH;
constexpr size_t OFF_G   = OFF_GL + (size_t)kB * kH;       // kB*kNG
constexpr size_t OFF_HX  = OFF_G + (size_t)kB * kNG;       // kB*kH
constexpr size_t OFF_CX  = OFF_HX + (size_t)kB * kH;       // kB*kH
constexpr size_t OFF_DC  = OFF_CX + (size_t)kB * kH;       // kB*kE
constexpr size_t OFF_FM  = OFF_DC + (size_t)kB * kE;       // kB ints
constexpr size_t OFF_FMM = OFF_FM + kB;
constexpr size_t WS_FLOATS = OFF_FMM + kB;                 // ≈265 MiB (PROVEN available)

// ---------------- sentinel (bail only) ----------------
__global__ __launch_bounds__(256) void sentinel_k(float* __restrict__ outSel, float val) {
  int i = blockIdx.x * blockDim.x + threadIdx.x;
  if (i < kT * kB) outSel[i] = val;
}

// ---------------- threefry2x32 (exact JAX) ----------------
__device__ __forceinline__ u32 rotl32(u32 v, int d) { return (v << d) | (v >> (32 - d)); }

__device__ __forceinline__ void tf2x32(u32 k0, u32 k1, u32 x0, u32 x1, u32& o0, u32& o1) {
  u32 ks2 = k0 ^ k1 ^ 0x1BD11BDAu;
  x0 += k0; x1 += k1;
#define RND_(r) { x0 += x1; x1 = rotl32(x1, r); x1 ^= x0; }
  RND_(13) RND_(15) RND_(26) RND_(6)   x0 += k1;  x1 += ks2 + 1u;
  RND_(17) RND_(29) RND_(16) RND_(24)  x0 += ks2; x1 += k0 + 2u;
  RND_(13) RND_(15) RND_(26) RND_(6)   x0 += k0;  x1 += k1 + 3u;
  RND_(17) RND_(29) RND_(16) RND_(24)  x0 += k1;  x1 += ks2 + 4u;
  RND_(13) RND_(15) RND_(26) RND_(6)   x0 += ks2; x1 += k0 + 5u;
#undef RND_
  o0 = x0; o1 = x1;
}

__device__ __forceinline__ float sigf(float x) { return 1.0f / (1.0f + expf(-x)); }

// ------- E precompute: coalesced W staging; EG/EP original layout -------
__global__ __launch_bounds__(512) void precompute_e(const float* __restrict__ ctx,
                                                    const float* __restrict__ Wg,
                                                    const float* __restrict__ bg,
                                                    const float* __restrict__ Wp,
                                                    const float* __restrict__ bp,
                                                    float* __restrict__ EG,
                                                    float* __restrict__ EP) {
  __shared__ float ctxs[8][512];
  __shared__ float Wgs[512][33];
  __shared__ float Wps[512][33];
  const int tid = threadIdx.x;
  const size_t m0 = (size_t)blockIdx.x * 8;
  for (int idx = tid; idx < 8 * 512; idx += 512) {
    ctxs[idx >> 9][idx & 511] = ctx[(m0 + (idx >> 9)) * 512 + (idx & 511)];
  }
  float accg[8] = {}, accp[8] = {};
  for (int k0 = 0; k0 < 512; k0 += 32) {
    __syncthreads();
    for (int idx = tid; idx < 512 * 32; idx += 512) {
      int row = idx >> 5, kk = idx & 31;
      Wgs[row][kk] = Wg[(size_t)row * 512 + k0 + kk];
      Wps[row][kk] = Wp[(size_t)row * 512 + k0 + kk];
    }
    __syncthreads();
#pragma unroll 4
    for (int kk = 0; kk < 32; ++kk) {
      float wg = Wgs[tid][kk], wp = Wps[tid][kk];
#pragma unroll
      for (int mi = 0; mi < 8; ++mi) {
        float a = ctxs[mi][k0 + kk];
        accg[mi] = fmaf(a, wg, accg[mi]);
        accp[mi] = fmaf(a, wp, accp[mi]);
      }
    }
  }
  float bgv = bg[tid], bpv = bp[tid];
#pragma unroll
  for (int mi = 0; mi < 8; ++mi) {
    size_t m = m0 + mi;
    EG[m * 512 + tid] = accg[mi] + bgv;
    EP[m * 512 + tid] = accp[mi] + bpv;
  }
}

// ------- b-tiled NT GEMM for LSTM gates (unchanged from R14) -------
template <int K, int NB, bool FIRST>
__global__ __launch_bounds__(512) void gemm_v2(const float* __restrict__ A,
                                               const float* __restrict__ W,
                                               const float* __restrict__ bias,
                                               const float* __restrict__ Cin,
                                               float* __restrict__ C, int N) {
  __shared__ float As[NB][K];
  __shared__ float Ws[512][33];
  const int b0 = blockIdx.y * NB;
  const int o0 = blockIdx.x * 512;
  const int tid = threadIdx.x;
  for (int idx = tid; idx < NB * K; idx += 512) {
    int bb = idx / K, k = idx % K;
    As[bb][k] = A[(size_t)(b0 + bb) * K + k];
  }
  float acc[NB] = {};
  for (int k0 = 0; k0 < K; k0 += 32) {
    __syncthreads();
    for (int idx = tid; idx < 512 * 32; idx += 512) {
      int row = idx >> 5, kk = idx & 31;
      Ws[row][kk] = W[(size_t)(o0 + row) * K + k0 + kk];
    }
    __syncthreads();
#pragma unroll 4
    for (int kk = 0; kk < 32; ++kk) {
      float w = Ws[tid][kk];
#pragma unroll
      for (int bb = 0; bb < NB; ++bb) acc[bb] = fmaf(As[bb][k0 + kk], w, acc[bb]);
    }
  }
  float bv = bias[o0 + tid];
#pragma unroll
  for (int bb = 0; bb < NB; ++bb) {
    size_t off = (size_t)(b0 + bb) * N + o0 + tid;
    C[off] = FIRST ? (acc[bb] + bv) : ((Cin[off] + acc[bb]) + bv);
  }
}

// ---------------- init state ----------------
__global__ __launch_bounds__(256) void init_k(const float* __restrict__ dec_in,
                                              const float* __restrict__ hx0,
                                              const float* __restrict__ cx0,
                                              float* __restrict__ dec, float* __restrict__ hx,
                                              float* __restrict__ cx, int* __restrict__ fm,
                                              int* __restrict__ fmm) {
  int i = blockIdx.x * blockDim.x + threadIdx.x;
  if (i < kB * kH) { hx[i] = hx0[i]; cx[i] = cx0[i]; }
  if (i < kB * kE) dec[i] = dec_in[i];
  if (i < kB) { fm[i] = 1; fmm[i] = 1; }
}

// ---------------- LSTM elementwise ----------------
__global__ __launch_bounds__(256) void lstm_act(const float* __restrict__ gates,
                                                float* __restrict__ hx, float* __restrict__ cx) {
  int i = blockIdx.x * blockDim.x + threadIdx.x;
  int b = i >> 9, h = i & (kH - 1);
  const float* g = gates + (size_t)b * kNG;
  float ig = g[h], fg = g[h + kH], cg = g[h + 2 * kH], og = g[h + 3 * kH];
  float cyv = sigf(fg) * cx[i] + sigf(ig) * tanhf(cg);
  float hyv = sigf(og) * tanhf(cyv);
  cx[i] = cyv;
  hx[i] = hyv;
}

// ======= fused per-b step: qp1 -> att1-u -> softmax -> gl -> qp2 -> att2-u -> sample =======
__global__ __launch_bounds__(512) void fused_step(
    const float* __restrict__ EG, const float* __restrict__ EP, const float* __restrict__ gWq,
    const float* __restrict__ gbq, const float* __restrict__ gv, const float* __restrict__ pWq,
    const float* __restrict__ pbq, const float* __restrict__ pv, const float* __restrict__ emb,
    const int* __restrict__ counts, float* __restrict__ HX, float* __restrict__ DC,
    int* __restrict__ fmask, int* __restrict__ fmmask, float* __restrict__ outP,
    float* __restrict__ outSel, int t) {
  __shared__ float Ws[512][33];   // 67.6 KB W staging (gWq then pWq)
  __shared__ float hs[512];       // hy
  __shared__ float qs[512];       // qp result (1 then 2)
  __shared__ float gvs[512];      // gv then pv
  __shared__ float gls[512];      // glimpse output
  __shared__ float u[128], sL[128], ex[128], kv[128];
  __shared__ float mred, sred, sMult;
  __shared__ int sIdx;

  const int b = blockIdx.x;
  const int tid = threadIdx.x;
  const int wave = tid >> 6, lane = tid & 63;

  hs[tid] = HX[(size_t)b * kH + tid];
  gvs[tid] = gv[tid];
  __syncthreads();

  // ---- qp1 = hs @ gWq^T + gbq (ascending-k fmaf per output; staged W) ----
  {
    float acc = 0.f;
    for (int k0 = 0; k0 < 512; k0 += 32) {
      __syncthreads();
      for (int idx = tid; idx < 512 * 32; idx += 512) {
        int row = idx >> 5, kk = idx & 31;
        Ws[row][kk] = gWq[(size_t)row * 512 + k0 + kk];
      }
      __syncthreads();
#pragma unroll 8
      for (int kk = 0; kk < 32; ++kk) acc = fmaf(hs[k0 + kk], Ws[tid][kk], acc);
    }
    qs[tid] = acc + gbq[tid];
  }
  __syncthreads();

  // ---- att1 u[s]: wave-per-s, lanes split h (stride 64), shuffle reduce ----
  for (int r = 0; r < 16; ++r) {
    int s = wave + 8 * r;
    const float* row = EG + ((size_t)s * kB + b) * kH;
    float a = 0.f;
#pragma unroll
    for (int i = 0; i < 8; ++i) {
      int h = lane + 64 * i;
      a = fmaf(gvs[h], tanhf(qs[h] + row[h]), a);
    }
#pragma unroll
    for (int off = 32; off > 0; off >>= 1) a += __shfl_xor(a, off);
    if (lane == 0) u[s] = a;
  }
  __syncthreads();

  // ---- softmax over s (serial max/sum semantics as R13) ----
  if (tid == 0) { float m = u[0]; for (int i = 1; i < 128; ++i) m = fmaxf(m, u[i]); mred = m; }
  __syncthreads();
  if (tid < 128) ex[tid] = expf(u[tid] - mred);
  __syncthreads();
  if (tid == 0) { float s = 0.f; for (int i = 0; i < 128; ++i) s += ex[i]; sred = s; }
  __syncthreads();
  if (tid < 128) ex[tid] = ex[tid] / sred; // P[s]
  __syncthreads();

  // ---- gl[h] = serial_s fmaf(EG[s][b][h], P[s]) (same order as R13 gl_k) ----
  {
    float acc = 0.f;
    for (int s = 0; s < 128; ++s) acc = fmaf(EG[((size_t)s * kB + b) * kH + tid], ex[s], acc);
    gls[tid] = acc;
  }
  __syncthreads();

  // ---- qp2 = gls @ pWq^T + pbq ----
  {
    float acc = 0.f;
    for (int k0 = 0; k0 < 512; k0 += 32) {
      __syncthreads();
      for (int idx = tid; idx < 512 * 32; idx += 512) {
        int row = idx >> 5, kk = idx & 31;
        Ws[row][kk] = pWq[(size_t)row * 512 + k0 + kk];
      }
      __syncthreads();
#pragma unroll 8
      for (int kk = 0; kk < 32; ++kk) acc = fmaf(gls[k0 + kk], Ws[tid][kk], acc);
    }
    qs[tid] = acc + pbq[tid];
    gvs[tid] = pv[tid];
  }
  __syncthreads();

  // ---- att2 u[s] on EP ----
  for (int r = 0; r < 16; ++r) {
    int s = wave + 8 * r;
    const float* row = EP + ((size_t)s * kB + b) * kH;
    float a = 0.f;
#pragma unroll
    for (int i = 0; i < 8; ++i) {
      int h = lane + 64 * i;
      a = fmaf(gvs[h], tanhf(qs[h] + row[h]), a);
    }
#pragma unroll
    for (int off = 32; off > 0; off >>= 1) a += __shfl_xor(a, off);
    if (lane == 0) u[s] = a;
  }
  __syncthreads();

  // ---- logits, softmax, gumbel, argmax, masks, gather (R13 semantics) ----
  if (tid < 128) sL[tid] = 10.0f * tanhf(u[tid]);
  __syncthreads();
  if (tid == 0) { float m = sL[0]; for (int i = 1; i < 128; ++i) m = fmaxf(m, sL[i]); mred = m; }
  __syncthreads();
  if (tid < 128) ex[tid] = expf(sL[tid] - mred);
  __syncthreads();
  if (tid == 0) { float s = 0.f; for (int i = 0; i < 128; ++i) s += ex[i]; sred = s; }
  __syncthreads();
  if (tid < 128) {
    u32 fk0, fk1;
    tf2x32(0u, 42u, 0u, (u32)t, fk0, fk1);
    // partitionable 32-bit path: counter (0, j); bits = out0 ^ out1
    u32 j = (u32)(b * kS + tid);
    u32 y0, y1;
    tf2x32(fk0, fk1, 0u, j, y0, y1);
    u32 bits = y0 ^ y1;
    float f = __uint_as_float(0x3f800000u | (bits >> 9)) - 1.0f;
    float uu = (f > 0.0f) ? f : 1.17549435082228751e-38f;
    float z = -logf(-logf(uu));
    kv[tid] = sL[tid] + z;
  }
  __syncthreads();
  if (tid == 0) {
    float best = kv[0];
    int ia = 0;
    for (int i = 1; i < 128; ++i)
      if (kv[i] > best) { best = kv[i]; ia = i; } // first-index tie-break
    int fm = fmask[b], fmm = fmmask[b];
    int idx = ia * fm;
    outSel[(size_t)t * kB + b] = (float)idx;
    fmask[b] = (idx != 0) ? fm : 0;
    fmmask[b] = (t == counts[b]) ? 0 : fmm;
    sIdx = idx;
    sMult = (float)(fm * fmm);
  }
  __syncthreads();
  if (tid < 128) outP[((size_t)b * kT + t) * kS + tid] = (ex[tid] / sred) * sMult;
  if (tid < 256) DC[(size_t)b * kE + tid] = emb[((size_t)sIdx * kB + b) * kE + tid];
}

// ---------------- final hx/cx copy ----------------
__global__ __launch_bounds__(256) void final_copy(const float* __restrict__ hx,
                                                  const float* __restrict__ cx,
                                                  float* __restrict__ o2, float* __restrict__ o3) {
  int i = blockIdx.x * blockDim.x + threadIdx.x;
  if (i < kB * kH) { o2[i] = hx[i]; o3[i] = cx[i]; }
}

extern "C" void kernel_launch(void* const* d_in, const int* in_sizes, int n_in, void* d_out,
                              int out_size, void* d_ws, size_t ws_size, hipStream_t stream) {
  const float* dec_in = (const float*)d_in[0];
  const float* emb = (const float*)d_in[1];
  const float* hx0 = (const float*)d_in[2];
  const float* cx0 = (const float*)d_in[3];
  const float* ctx = (const float*)d_in[4];
  const int* counts = (const int*)d_in[5];
  const float* Wi = (const float*)d_in[7];
  const float* bi = (const float*)d_in[8];
  const float* Wh = (const float*)d_in[9];
  const float* bh = (const float*)d_in[10];
  const float* gWq = (const float*)d_in[11];
  const float* gbq = (const float*)d_in[12];
  const float* gWr = (const float*)d_in[13];
  const float* gbr = (const float*)d_in[14];
  const float* gv = (const float*)d_in[15];
  const float* pWq = (const float*)d_in[16];
  const float* pbq = (const float*)d_in[17];
  const float* pWr = (const float*)d_in[18];
  const float* pbr = (const float*)d_in[19];
  const float* pv = (const float*)d_in[20];

  float* out = (float*)d_out;
  float* outP = out;                          // (B*T, S)
  float* outSel = out + (size_t)kB * kT * kS; // (T, B)
  float* outHx = outSel + (size_t)kT * kB;    // (B, H)
  float* outCx = outHx + (size_t)kB * kH;     // (B, H)

  if (ws_size < WS_FLOATS * sizeof(float)) {
    double wsMB = (double)ws_size / (1024.0 * 1024.0);
    if (wsMB > 80000.0) wsMB = 80000.0;
    hipLaunchKernelGGL(sentinel_k, dim3((kT * kB + 255) / 256), dim3(256), 0, stream, outSel,
                       (float)(1000.0 + wsMB));
    return;
  }

  float* base = (float*)d_ws;
  float* EG = base + OFF_EG;
  float* EP = base + OFF_EP;
  float* G  = base + OFF_G;
  float* HX = base + OFF_HX;
  float* CX = base + OFF_CX;
  float* DC = base + OFF_DC;
  int* FM  = (int*)(base + OFF_FM);
  int* FMM = (int*)(base + OFF_FMM);

  hipLaunchKernelGGL(precompute_e, dim3(kS * kB / 8), dim3(512), 0, stream, ctx, gWr, gbr, pWr,
                     pbr, EG, EP);
  hipLaunchKernelGGL(init_k, dim3(kB * kH / 256), dim3(256), 0, stream, dec_in, hx0, cx0, DC, HX,
                     CX, FM, FMM);

  for (int t = 0; t < kT; ++t) {
    hipLaunchKernelGGL((gemm_v2<256, 8, true>), dim3(4, 64), dim3(512), 0, stream, DC, Wi, bi,
                       (const float*)nullptr, G, kNG);
    hipLaunchKernelGGL((gemm_v2<512, 8, false>), dim3(4, 64), dim3(512), 0, stream, HX, Wh, bh, G,
                       G, kNG);
    hipLaunchKernelGGL(lstm_act, dim3(kB * kH / 256), dim3(256), 0, stream, G, HX, CX);
    hipLaunchKernelGGL(fused_step, dim3(kB), dim3(512), 0, stream, EG, EP, gWq, gbq, gv, pWq, pbq,
                       pv, emb, counts, HX, DC, FM, FMM, outP, outSel, t);
  }
  hipLaunchKernelGGL(final_copy, dim3(kB * kH / 256), dim3(256), 0, stream, HX, CX, outHx, outCx);
}